// Round 6
// baseline (91.902 us; speedup 1.0000x reference)
//
#include <hip/hip_runtime.h>

// Fused 3-level B3-spline UWT, fp32. x:(16,1024,1024)->out:(16,4,1024,1024)=[w1,w2,w3,c3].
// 64x64 tile, 92x96 input tile, 2 barriers, 77 KB LDS -> 2 blocks/CU.
// passA: horizontal a-trous cascade h1->h2->h3 IN-PLACE in a 48-float register
//        buffer (440 FMA vs 672 dense); u2 = h2 center comes free.
// u2/u3 LDS tiles are COLUMN-MAJOR f4 (pitch 77/93 rows, ==5 mod 8 -> bank
// stride 20 words, uniform 2 lanes/bank-quartet = b128 minimum) so passB reads
// are contiguous immediate-offset ds_read_b128 with zero index math.

typedef float f4v __attribute__((ext_vector_type(4)));

constexpr int TB   = 256;
constexpr int TROW = 64;
constexpr int TCOL = 64;
constexpr int VH   = 14;          // vertical halo (2+4+8)
constexpr int XR   = 92;          // TROW + 28
constexpr int XP   = 96;          // xs pitch (floats)
constexpr int U2P  = 77;          // u2 column pitch (f4 rows), 76 valid rows
constexpr int U3P  = 93;          // u3 column pitch (f4 rows), 92 valid rows
constexpr int HW   = 1024 * 1024;

__device__ constexpr float K13[13] = {
    1.f/256, 4.f/256, 10.f/256, 20.f/256, 31.f/256, 40.f/256, 44.f/256,
    40.f/256, 31.f/256, 20.f/256, 10.f/256, 4.f/256, 1.f/256};
__device__ constexpr float K29[29] = {
    1.f/4096,   4.f/4096,  10.f/4096,  20.f/4096,  35.f/4096,  56.f/4096,
    84.f/4096, 120.f/4096, 161.f/4096, 204.f/4096, 246.f/4096, 284.f/4096,
    315.f/4096, 336.f/4096, 344.f/4096, 336.f/4096, 315.f/4096, 284.f/4096,
    246.f/4096, 204.f/4096, 161.f/4096, 120.f/4096,  84.f/4096,  56.f/4096,
    35.f/4096,  20.f/4096,  10.f/4096,   4.f/4096,   1.f/4096};

__device__ __forceinline__ int refl(int i) {
    return i < 0 ? -i : (i >= 1024 ? 2046 - i : i);
}
// xs: row-major, f4-granular XOR swizzle (bijective: XOR acts on low 3 bits of c4).
__device__ __forceinline__ int xidx(int r, int c4) { return r * XP + 4 * (c4 ^ (r & 7)); }

__global__ __launch_bounds__(TB, 2)
void uwt3_kernel(const float* __restrict__ x, float* __restrict__ out)
{
    __shared__ float xs[XR * XP];      // 35.3 KB
    __shared__ f4v   u2s[16 * U2P];    // 19.3 KB, [quartet][row]
    __shared__ f4v   u3s[16 * U3P];    // 23.3 KB, [quartet][row]

    const int tid = threadIdx.x;

    // bijective XCD chunk swizzle (4096 % 8 == 0)
    const int flat = blockIdx.x;
    const int swz  = (flat & 7) * 512 + (flat >> 3);
    const int bxi = swz & 15;
    const int byi = (swz >> 4) & 15;
    const int bz  = swz >> 8;
    const int bx = bxi * TCOL;
    const int by = byi * TROW;

    const float* xp = x + (size_t)bz * HW;
    float* op = out + (size_t)bz * 4 * HW;

    // ---- load x tile: rows [by-14, by+78), cols [bx-16, bx+80) ----
    if (bxi != 0 && bxi != 15) {
        for (int e = tid; e < XR * 24; e += TB) {
            const int r = e / 24, m = e - r * 24;
            const int gr = refl(by - VH + r);
            const f4v v = *(const f4v*)(xp + (size_t)gr * 1024 + (bx - 16 + 4 * m));
            *(f4v*)(xs + xidx(r, m)) = v;
        }
    } else {
        for (int e = tid; e < XR * 96; e += TB) {
            const int r = e / 96, c = e - r * 96;
            const int gr = refl(by - VH + r);
            const int gc = refl(bx - 16 + c);
            xs[xidx(r, c >> 2) + (c & 3)] = xp[(size_t)gr * 1024 + gc];
        }
    }
    __syncthreads();

    // ---- passA: horizontal cascade -> u2 (= h2 center), u3 (= h3) ----
    // F covers xs float cols [16gi, 16gi+48). In-place:
    //   h1[i]=conv_d1(x)   i in [2,42) ; h2[i]=conv_d2(h1) i in [2,34)
    //   u2 = h2 @ F[10..25];  h3[i]=conv_d4(h2) i in [2,18); u3 = h3 @ F[2..17]
    for (int t = tid; t < XR * 4; t += TB) {
        const int gi = t & 3;
        const int rp = t >> 2;
        float F[48];
#pragma unroll
        for (int m = 0; m < 12; ++m)
            *(f4v*)&F[4 * m] = *(const f4v*)(xs + xidx(rp, 4 * gi + m));
#pragma unroll
        for (int i = 2; i < 42; ++i)
            F[i] = 0.0625f * (F[i] + F[i + 4]) + 0.25f * (F[i + 1] + F[i + 3])
                 + 0.375f * F[i + 2];
#pragma unroll
        for (int i = 2; i < 34; ++i)
            F[i] = 0.0625f * (F[i] + F[i + 8]) + 0.25f * (F[i + 2] + F[i + 6])
                 + 0.375f * F[i + 4];
        if (rp >= 8 && rp < 84) {
#pragma unroll
            for (int k = 0; k < 4; ++k) {
                const f4v v = {F[10 + 4*k], F[11 + 4*k], F[12 + 4*k], F[13 + 4*k]};
                u2s[(4 * gi + k) * U2P + (rp - 8)] = v;
            }
        }
#pragma unroll
        for (int i = 2; i < 18; ++i)
            F[i] = 0.0625f * (F[i] + F[i + 16]) + 0.25f * (F[i + 4] + F[i + 12])
                 + 0.375f * F[i + 8];
#pragma unroll
        for (int k = 0; k < 4; ++k) {
            const f4v v = {F[2 + 4*k], F[3 + 4*k], F[4 + 4*k], F[5 + 4*k]};
            u3s[(4 * gi + k) * U3P + rp] = v;
        }
    }
    __syncthreads();

    // ---- passB: vertical convs + outputs; thread = (f4-col, 4-row strip) ----
    const int fc = tid & 15;
    const int r0 = (tid >> 4) * 4;
    const size_t gbase = (size_t)(by + r0) * 1024 + bx + 4 * fc;

    // c1 = V1(U1 x) from xs; capture x center for w1
    f4v c1[4], xc[4];
    {
        f4v u1r[8];
#pragma unroll
        for (int i = 0; i < 8; ++i) {
            float f[12];
#pragma unroll
            for (int m = 0; m < 3; ++m)
                *(f4v*)&f[4 * m] = *(const f4v*)(xs + xidx(r0 + 12 + i, fc + 3 + m));
            if (i >= 2 && i < 6) xc[i - 2] = *(const f4v*)&f[4];
            f4v a;
#pragma unroll
            for (int q = 0; q < 4; ++q)
                a[q] = 0.0625f * (f[2 + q] + f[6 + q]) + 0.25f * (f[3 + q] + f[5 + q])
                     + 0.375f * f[4 + q];
            u1r[i] = a;
        }
#pragma unroll
        for (int j = 0; j < 4; ++j)
            c1[j] = 0.0625f * (u1r[j] + u1r[j + 4]) + 0.25f * (u1r[j + 1] + u1r[j + 3])
                  + 0.375f * u1r[j + 2];
    }
#pragma unroll
    for (int j = 0; j < 4; ++j)
        __builtin_nontemporal_store(xc[j] - c1[j],
            (f4v*)(op + 0 * HW + gbase + (size_t)j * 1024));

    // c2 = V2 u2 : contiguous column read, immediate offsets
    {
        const f4v* b2 = u2s + fc * U2P + r0;
        f4v c2[4] = {{0,0,0,0},{0,0,0,0},{0,0,0,0},{0,0,0,0}};
#pragma unroll
        for (int i = 0; i < 16; ++i) {
            const f4v v = b2[i];
#pragma unroll
            for (int j = 0; j < 4; ++j) {
                const int m = i - j;
                if (m >= 0 && m <= 12) c2[j] += K13[m] * v;
            }
        }
#pragma unroll
        for (int j = 0; j < 4; ++j)
            __builtin_nontemporal_store(c1[j] - c2[j],
                (f4v*)(op + 1 * HW + gbase + (size_t)j * 1024));
        // reuse c2 as "prev" for level 3
        c1[0] = c2[0]; c1[1] = c2[1]; c1[2] = c2[2]; c1[3] = c2[3];
    }

    // c3 = V3 u3 : contiguous column read, immediate offsets
    {
        const f4v* b3 = u3s + fc * U3P + r0;
        f4v c3[4] = {{0,0,0,0},{0,0,0,0},{0,0,0,0},{0,0,0,0}};
#pragma unroll
        for (int i = 0; i < 32; ++i) {
            const f4v v = b3[i];
#pragma unroll
            for (int j = 0; j < 4; ++j) {
                const int m = i - j;
                if (m >= 0 && m <= 28) c3[j] += K29[m] * v;
            }
        }
#pragma unroll
        for (int j = 0; j < 4; ++j) {
            __builtin_nontemporal_store(c1[j] - c3[j],
                (f4v*)(op + 2 * HW + gbase + (size_t)j * 1024));
            __builtin_nontemporal_store(c3[j],
                (f4v*)(op + 3 * HW + gbase + (size_t)j * 1024));
        }
    }
}

extern "C" void kernel_launch(void* const* d_in, const int* in_sizes, int n_in,
                              void* d_out, int out_size, void* d_ws, size_t ws_size,
                              hipStream_t stream)
{
    const float* x = (const float*)d_in[0];
    float* out = (float*)d_out;
    uwt3_kernel<<<dim3(4096), dim3(TB), 0, stream>>>(x, out);
}